// Round 21
// baseline (170.236 us; speedup 1.0000x reference)
//
#include <hip/hip_runtime.h>

// Pipeline (4 dispatches): cvt3+bias_prep -> GEMM qkv 256x128 tile (8 waves) + fused
//   bias/l2norm/scale/split (V written transposed+permuted) -> flash attn (8 waves,
//   QBLK=128, no split) -> GEMM proj(f32+bias)
// B=2 L=2048 C=1024 H=16 D=64. All matmuls bf16 MFMA 16x16x32, f32 accumulate.

typedef __bf16 bf16x8 __attribute__((ext_vector_type(8)));
typedef __bf16 bf16x4 __attribute__((ext_vector_type(4)));
typedef float  f32x4  __attribute__((ext_vector_type(4)));

#define BB 2
#define LL 2048
#define CC 1024
#define HH 16
#define DD 64
#define LOG2E 1.44269504088896f

__device__ __forceinline__ f32x4 mfma_16x16x32(bf16x8 a, bf16x8 b, f32x4 c) {
    return __builtin_amdgcn_mfma_f32_16x16x32_bf16(a, b, c, 0, 0, 0);
}

// async global->LDS, 16B per lane; LDS dest = wave-uniform base + lane*16
__device__ __forceinline__ void gload_lds16(const __bf16* g, __bf16* lds) {
    __builtin_amdgcn_global_load_lds(
        (const __attribute__((address_space(1))) unsigned int*)g,
        (__attribute__((address_space(3))) unsigned int*)lds,
        16, 0, 0);
}

__device__ __forceinline__ unsigned pk_bf16(float a, float b) {
    unsigned short ua = __builtin_bit_cast(unsigned short, (__bf16)a);
    unsigned short ub = __builtin_bit_cast(unsigned short, (__bf16)b);
    return (unsigned)ua | ((unsigned)ub << 16);
}

// ---------------- merged: f32->bf16 cvt (blocks 0..8191) + bias_prep (8192..10239) -------
__global__ __launch_bounds__(256) void cvt3b_kernel(
    const float* __restrict__ x, const float* __restrict__ wq, const float* __restrict__ wp,
    const float* __restrict__ bias,
    __bf16* __restrict__ xb, __bf16* __restrict__ wqb, __bf16* __restrict__ wpb,
    __bf16* __restrict__ bias_bf) {
    const int tid = threadIdx.x;
    if (blockIdx.x < 8192) {
        const int i = blockIdx.x * 256 + tid;   // f32x4 index, 2097152 total
        const float* src; __bf16* dst; int off;
        if (i < 1048576)      { src = x;  dst = xb;  off = i; }
        else if (i < 1835008) { src = wq; dst = wqb; off = i - 1048576; }
        else                  { src = wp; dst = wpb; off = i - 1835008; }
        float4 v = reinterpret_cast<const float4*>(src)[off];
        bf16x4 o;
        o[0] = (__bf16)v.x; o[1] = (__bf16)v.y; o[2] = (__bf16)v.z; o[3] = (__bf16)v.w;
        reinterpret_cast<bf16x4*>(dst)[off] = o;
    } else {
        __shared__ float wmax[4];
        const int l = blockIdx.x - 8192;        // bias row 0..2047
        const int w = tid >> 6;
        float4 a = reinterpret_cast<const float4*>(bias + (size_t)l * 2048)[tid];
        float4 b = reinterpret_cast<const float4*>(bias + (size_t)l * 2048 + 1024)[tid];
        float m = fmaxf(fmaxf(fmaxf(a.x, a.y), fmaxf(a.z, a.w)),
                        fmaxf(fmaxf(b.x, b.y), fmaxf(b.z, b.w)));
#pragma unroll
        for (int off = 1; off < 64; off <<= 1) m = fmaxf(m, __shfl_xor(m, off, 64));
        if ((tid & 63) == 0) wmax[w] = m;
        __syncthreads();
        float M = fmaxf(fmaxf(wmax[0], wmax[1]), fmaxf(wmax[2], wmax[3]));
        bf16x4 o0, o1;
        o0[0] = (__bf16)((a.x - M) * LOG2E); o0[1] = (__bf16)((a.y - M) * LOG2E);
        o0[2] = (__bf16)((a.z - M) * LOG2E); o0[3] = (__bf16)((a.w - M) * LOG2E);
        o1[0] = (__bf16)((b.x - M) * LOG2E); o1[1] = (__bf16)((b.y - M) * LOG2E);
        o1[2] = (__bf16)((b.z - M) * LOG2E); o1[3] = (__bf16)((b.w - M) * LOG2E);
        reinterpret_cast<bf16x4*>(bias_bf + (size_t)l * 2048)[tid] = o0;
        reinterpret_cast<bf16x4*>(bias_bf + (size_t)l * 2048 + 1024)[tid] = o1;
    }
}

// ---------------- QKV GEMM 256x128 tile, 512 threads (8 waves 4Mx2N) + fused epilogue ----
// V written directly as Vp (B,H,D,perm(L)): pos = (k[3:2]<<3)|(k[4]<<2)|k[1:0] per 32-block.
__global__ __launch_bounds__(512) void gemm_qkv_fused_kernel(
    const __bf16* __restrict__ A, const __bf16* __restrict__ Bm,
    const float* __restrict__ q_bias, const float* __restrict__ v_bias,
    const float* __restrict__ scale_mul,
    __bf16* __restrict__ Qw, __bf16* __restrict__ Kw, __bf16* __restrict__ Vp) {
    __shared__ __bf16 As[256 * 64];   // LDS[row][c] = A[row][c ^ ((row&7)<<3 elems)]
    __shared__ __bf16 Bs[128 * 64];
    const int tid = threadIdx.x;
    const int K = 1024;
    // bijective XCD swizzle (nwg = 384, %8==0)
    const int nwg = gridDim.x * gridDim.y;
    const int flat = blockIdx.y * gridDim.x + blockIdx.x;
    const int wg = (flat & 7) * (nwg >> 3) + (flat >> 3);
    const int m0 = (wg % gridDim.x) * 256, n0 = (wg / gridDim.x) * 128;
    const int w  = tid >> 6, l = tid & 63;
    const int wr = (w >> 1) * 64, wc = (w & 1) * 64;   // wave tile: rows wr..+63, cols wc..+63
    const int lr = l & 15, lg = l >> 4;
    const int rmask = (lr & 7) << 4;
    f32x4 acc[4][4] = {};
    const int lrow = l >> 3;
    const int celem = (((l & 7) ^ lrow) << 3);

    for (int kt = 0; kt < K; kt += 64) {
        __syncthreads();
        // staging: 384 rows (A:0..255, B:256..383); wave w covers 6 chunks of 8 rows
#pragma unroll
        for (int i = 0; i < 6; ++i) {
            const int urow = w * 48 + i * 8;           // chunk-aligned: wholly A or wholly B
            if (urow < 256) {
                gload_lds16(A + (size_t)(m0 + urow + lrow) * K + kt + celem, &As[urow * 64]);
            } else {
                const int br = urow - 256;
                gload_lds16(Bm + (size_t)(n0 + br + lrow) * K + kt + celem, &Bs[br * 64]);
            }
        }
        asm volatile("s_waitcnt vmcnt(0)" ::: "memory");
        __syncthreads();
#pragma unroll
        for (int kk = 0; kk < 2; ++kk) {
            bf16x8 af[4], bfr[4];
#pragma unroll
            for (int m = 0; m < 4; ++m)
                af[m] = *reinterpret_cast<const bf16x8*>(
                    (char*)As + (wr + m * 16 + lr) * 128 + ((kk * 64 + lg * 16) ^ rmask));
#pragma unroll
            for (int n = 0; n < 4; ++n)
                bfr[n] = *reinterpret_cast<const bf16x8*>(
                    (char*)Bs + (wc + n * 16 + lr) * 128 + ((kk * 64 + lg * 16) ^ rmask));
#pragma unroll
            for (int m = 0; m < 4; ++m)
#pragma unroll
                for (int n = 0; n < 4; ++n)
                    acc[m][n] = mfma_16x16x32(af[m], bfr[n], acc[m][n]);
        }
    }

    // ---- fused epilogue (wave cols gcbase..gcbase+63 = exactly one head of one type) ----
    const int gcbase = n0 + wc;
    const int type = gcbase >> 10;           // 0=q, 1=k, 2=v
    const int h = (gcbase & 1023) >> 6;
    float qscale = 1.0f;
    if (type == 0) qscale = __expf(fminf(scale_mul[h], 4.60517019f)) * LOG2E;
    __bf16* dst = (type == 0) ? Qw : Kw;

#pragma unroll
    for (int m = 0; m < 4; ++m) {
        if (type != 1) {                     // q/v bias (k has zero bias)
            const float* bptr = (type == 0) ? q_bias : v_bias;
#pragma unroll
            for (int n = 0; n < 4; ++n) {
                float bv = bptr[(gcbase & 1023) + n * 16 + lr];
#pragma unroll
                for (int r = 0; r < 4; ++r) acc[m][n][r] += bv;
            }
        }
        const int rowg = m0 + wr + m * 16 + lg * 4;
        if (type < 2) {
            float rs[4];
#pragma unroll
            for (int r = 0; r < 4; ++r) {
                float ss = 0.f;
#pragma unroll
                for (int n = 0; n < 4; ++n) ss += acc[m][n][r] * acc[m][n][r];
                rs[r] = ss;
            }
#pragma unroll
            for (int off = 1; off < 16; off <<= 1)
#pragma unroll
                for (int r = 0; r < 4; ++r) rs[r] += __shfl_xor(rs[r], off, 64);
#pragma unroll
            for (int r = 0; r < 4; ++r)
                rs[r] = ((type == 0) ? qscale : 1.0f) / fmaxf(sqrtf(rs[r]), 1e-12f);
#pragma unroll
            for (int n = 0; n < 4; ++n) {
                const int d = n * 16 + lr;
#pragma unroll
                for (int r = 0; r < 4; ++r) {
                    const int row = rowg + r;
                    const int bb = row >> 11, ll = row & 2047;
                    dst[((size_t)((bb << 4) + h) * 2048 + ll) * 64 + d] =
                        (__bf16)(acc[m][n][r] * rs[r]);
                }
            }
        } else {
            // V: direct transposed+permuted write. rowg%4==0 -> 4 consecutive Vp positions.
            const int bb = rowg >> 11, ll0 = rowg & 2047;
            const int posb = (ll0 & ~31) | (((ll0 >> 2) & 3) << 3) | (((ll0 >> 4) & 1) << 2);
#pragma unroll
            for (int n = 0; n < 4; ++n) {
                const int d = n * 16 + lr;
                bf16x4 vv;
#pragma unroll
                for (int r = 0; r < 4; ++r) vv[r] = (__bf16)acc[m][n][r];
                *reinterpret_cast<bf16x4*>(
                    Vp + ((size_t)((bb << 4) + h) * 64 + d) * 2048 + posb) = vv;
            }
        }
    }
}

// ---------------- GEMM proj: C = A*B^T + bias (f32 out), 128^2, m97 + XCD swz ----------
__global__ __launch_bounds__(256) void gemm_proj_kernel(
    const __bf16* __restrict__ A, const __bf16* __restrict__ Bm,
    float* __restrict__ Cf, const float* __restrict__ bias, int M, int N, int K) {
    __shared__ __bf16 As[128 * 64];
    __shared__ __bf16 Bs[128 * 64];
    const int tid = threadIdx.x;
    const int nwg = gridDim.x * gridDim.y;
    const int flat = blockIdx.y * gridDim.x + blockIdx.x;
    const int wg = (flat & 7) * (nwg >> 3) + (flat >> 3);
    const int m0 = (wg % gridDim.x) * 128, n0 = (wg / gridDim.x) * 128;
    const int w  = tid >> 6, l = tid & 63;
    const int wr = (w >> 1) * 64, wc = (w & 1) * 64;
    const int lr = l & 15, lg = l >> 4;
    const int rmask = (lr & 7) << 4;
    f32x4 acc[4][4] = {};
    const int lrow = l >> 3;
    const int celem = (((l & 7) ^ lrow) << 3);

    for (int kt = 0; kt < K; kt += 64) {
        __syncthreads();
#pragma unroll
        for (int i = 0; i < 4; ++i) {
            const int row = w * 32 + i * 8;
            gload_lds16(A + (size_t)(m0 + row + lrow) * K + kt + celem, &As[row * 64]);
            gload_lds16(Bm + (size_t)(n0 + row + lrow) * K + kt + celem, &Bs[row * 64]);
        }
        asm volatile("s_waitcnt vmcnt(0)" ::: "memory");
        __syncthreads();
#pragma unroll
        for (int kk = 0; kk < 2; ++kk) {
            bf16x8 af[4], bfr[4];
#pragma unroll
            for (int m = 0; m < 4; ++m)
                af[m] = *reinterpret_cast<const bf16x8*>(
                    (char*)As + (wr + m * 16 + lr) * 128 + ((kk * 64 + lg * 16) ^ rmask));
#pragma unroll
            for (int n = 0; n < 4; ++n)
                bfr[n] = *reinterpret_cast<const bf16x8*>(
                    (char*)Bs + (wc + n * 16 + lr) * 128 + ((kk * 64 + lg * 16) ^ rmask));
#pragma unroll
            for (int m = 0; m < 4; ++m)
#pragma unroll
                for (int n = 0; n < 4; ++n)
                    acc[m][n] = mfma_16x16x32(af[m], bfr[n], acc[m][n]);
        }
    }
#pragma unroll
    for (int m = 0; m < 4; ++m)
#pragma unroll
        for (int n = 0; n < 4; ++n) {
            const int row = m0 + wr + m * 16 + lg * 4;
            const int col = n0 + wc + n * 16 + lr;
#pragma unroll
            for (int r = 0; r < 4; ++r)
                Cf[(size_t)(row + r) * N + col] = acc[m][n][r] + bias[col];
        }
}

// ---------------- flash attention: R19-exact. 8 waves (512 thr), QBLK=128, no split ------
// grid (bh=32, qb=16) = 512 blocks = exact 2/CU at (512,6); normalized bf16 out direct.
// NOTE: (512,6) + natural bh-fastest dispatch order is load-bearing (R15 lesson).
__global__ __launch_bounds__(512, 6) void attn_kernel(
    const __bf16* __restrict__ Q, const __bf16* __restrict__ K,
    const __bf16* __restrict__ Vp, const __bf16* __restrict__ biasB,
    __bf16* __restrict__ Octx) {
    __shared__ __bf16 KVs[2][2][64 * 64];   // [buf][K/V]; LDS[row][c]=G[row][c^((row&7)<<4)]
    const int bh = blockIdx.x, qb = blockIdx.y;
    const int tid = threadIdx.x;
    const int w = tid >> 6, l = tid & 63;
    const int lr = l & 15, lg = l >> 4;
    const int rmask = (lr & 7) << 4;
    const int b = bh >> 4, h = bh & 15;
    const size_t base = (size_t)bh * LL * DD;

    const int gq = qb * 128 + w * 16 + lr;
    bf16x8 qf[2];
    qf[0] = *reinterpret_cast<const bf16x8*>(Q + base + (size_t)gq * 64 + lg * 8);
    qf[1] = *reinterpret_cast<const bf16x8*>(Q + base + (size_t)gq * 64 + 32 + lg * 8);
    const __bf16* brow = biasB + (size_t)gq * 2048 + lg * 4;

    bf16x8 ones;
#pragma unroll
    for (int j = 0; j < 8; ++j) ones[j] = (__bf16)1.0f;

    // staging: wave w covers rows [w*8, w*8+8); lane: row w*8+(l>>3), 8 elems at (l&7)*8
    const int srow = w * 8 + (l >> 3);
    const int sce  = (l & 7) * 8;                  // element col
    const int smask = (srow & 7) << 4;             // (l>>3)<<4
    const __bf16* kgbase = K  + base + (size_t)srow * 64   + sce;
    const __bf16* vgbase = Vp + base + (size_t)srow * 2048 + sce;

    bf16x8 k0, v0;
    auto stage_regs = [&](int kb) {
        k0 = *reinterpret_cast<const bf16x8*>(kgbase + (size_t)kb * 64 * 64);
        v0 = *reinterpret_cast<const bf16x8*>(vgbase + kb * 64);
    };
    auto write_lds = [&](int buf) {
        *reinterpret_cast<bf16x8*>((char*)KVs[buf][0] + srow * 128 + ((sce * 2) ^ smask)) = k0;
        *reinterpret_cast<bf16x8*>((char*)KVs[buf][1] + srow * 128 + ((sce * 2) ^ smask)) = v0;
    };

    stage_regs(0);
    write_lds(0);

    f32x4 Oa[4] = {};
    f32x4 ls = {};
    int cur = 0;

    bf16x4 bcur[4];
#pragma unroll
    for (int t = 0; t < 4; ++t)
        bcur[t] = *reinterpret_cast<const bf16x4*>(brow + t * 16);

    for (int kb = 0; kb < 32; ++kb) {
        __syncthreads();                    // buf[cur] published; buf[cur^1] free
        if (kb < 31) stage_regs(kb + 1);

        bf16x4 bnext[4];
        if (kb < 31) {
#pragma unroll
            for (int t = 0; t < 4; ++t)
                bnext[t] = *reinterpret_cast<const bf16x4*>(brow + (kb + 1) * 64 + t * 16);
        }

        const char* Kc = (const char*)KVs[cur][0];
        const char* Vc = (const char*)KVs[cur][1];

        // acc init = bias'(bf16); no cexp (cancels in O = sum(pv)/sum(p))
        f32x4 sa[4];
#pragma unroll
        for (int t = 0; t < 4; ++t)
#pragma unroll
            for (int r = 0; r < 4; ++r)
                sa[t][r] = (float)bcur[t][r];

        // S^T·log2e + bias' : lane q=lr, k = 16t+4lg+r
#pragma unroll
        for (int t = 0; t < 4; ++t) {
            const char* kr = Kc + (t * 16 + lr) * 128;
            bf16x8 kf0 = *reinterpret_cast<const bf16x8*>(kr + ((lg * 16) ^ rmask));
            bf16x8 kf1 = *reinterpret_cast<const bf16x8*>(kr + ((64 + lg * 16) ^ rmask));
            sa[t] = mfma_16x16x32(kf0, qf[0], sa[t]);
            sa[t] = mfma_16x16x32(kf1, qf[1], sa[t]);
        }

        // softmax: p = exp2(sa); pack lane-local values into A-operand slots
        float p[4][4];
#pragma unroll
        for (int t = 0; t < 4; ++t)
#pragma unroll
            for (int r = 0; r < 4; ++r)
                p[t][r] = exp2f(sa[t][r]);
        union Upa { unsigned u[4]; bf16x8 v; } pa0, pa1;
        pa0.u[0] = pk_bf16(p[0][0], p[0][1]); pa0.u[1] = pk_bf16(p[0][2], p[0][3]);
        pa0.u[2] = pk_bf16(p[1][0], p[1][1]); pa0.u[3] = pk_bf16(p[1][2], p[1][3]);
        pa1.u[0] = pk_bf16(p[2][0], p[2][1]); pa1.u[1] = pk_bf16(p[2][2], p[2][3]);
        pa1.u[2] = pk_bf16(p[3][0], p[3][1]); pa1.u[3] = pk_bf16(p[3][2], p[3][3]);

        // row-sum via MFMA (B = ones): ls rows = Oa rows
        ls = mfma_16x16x32(pa0.v, ones, ls);
        ls = mfma_16x16x32(pa1.v, ones, ls);

        // O += P·V : V pre-permuted globally -> contiguous b128 reads (same pattern as K)
#pragma unroll
        for (int t = 0; t < 4; ++t) {
            const char* vr = Vc + (t * 16 + lr) * 128;
            bf16x8 vf0 = *reinterpret_cast<const bf16x8*>(vr + ((lg * 16) ^ rmask));
            bf16x8 vf1 = *reinterpret_cast<const bf16x8*>(vr + ((64 + lg * 16) ^ rmask));
            Oa[t] = mfma_16x16x32(pa0.v, vf0, Oa[t]);
            Oa[t] = mfma_16x16x32(pa1.v, vf1, Oa[t]);
        }

        if (kb < 31) {
            write_lds(cur ^ 1);             // write-late; dep on loads forces vmcnt
#pragma unroll
            for (int t = 0; t < 4; ++t) bcur[t] = bnext[t];
        }
        cur ^= 1;
    }

    // normalized bf16 output direct (inv from MFMA row-sum; ls rows == Oa rows)
    float inv[4];
#pragma unroll
    for (int r = 0; r < 4; ++r) inv[r] = 1.0f / ls[r];
#pragma unroll
    for (int t = 0; t < 4; ++t)
#pragma unroll
        for (int r = 0; r < 4; ++r) {
            const int row = qb * 128 + w * 16 + lg * 4 + r;
            Octx[((size_t)(b * 2048 + row)) * 1024 + h * 64 + t * 16 + lr] =
                (__bf16)(Oa[t][r] * inv[r]);
        }
}

// ---------------- launch ----------------
extern "C" void kernel_launch(void* const* d_in, const int* in_sizes, int n_in,
                              void* d_out, int out_size, void* d_ws, size_t ws_size,
                              hipStream_t stream) {
    const float* x         = (const float*)d_in[0];
    const float* attn_bias = (const float*)d_in[1];
    const float* W_qkv     = (const float*)d_in[2];
    const float* q_bias    = (const float*)d_in[3];
    const float* v_bias    = (const float*)d_in[4];
    const float* scale_mul = (const float*)d_in[5];
    const float* W_proj    = (const float*)d_in[6];
    const float* b_proj    = (const float*)d_in[7];
    float* out = (float*)d_out;

    char* ws = (char*)d_ws;
    size_t off = 0;
    auto alloc = [&](size_t bytes) {
        void* p = ws + off;
        off = (off + bytes + 255) & ~(size_t)255;
        return p;
    };
    __bf16* xb      = (__bf16*)alloc((size_t)4096 * 1024 * 2);         //  8 MB
    __bf16* wqkvb   = (__bf16*)alloc((size_t)3072 * 1024 * 2);         //  6 MB
    __bf16* wprojb  = (__bf16*)alloc((size_t)1024 * 1024 * 2);         //  2 MB
    __bf16* Qw      = (__bf16*)alloc((size_t)BB * HH * LL * DD * 2);   //  8 MB
    __bf16* Kw      = (__bf16*)alloc((size_t)BB * HH * LL * DD * 2);   //  8 MB
    __bf16* Oc      = (__bf16*)alloc((size_t)4096 * 1024 * 2);         //  8 MB
    __bf16* biasB   = (__bf16*)alloc((size_t)2048 * 2048 * 2);         //  8 MB
    __bf16* Vp      = (__bf16*)alloc((size_t)BB * HH * LL * DD * 2);   //  8 MB

    cvt3b_kernel<<<10240, 256, 0, stream>>>(x, W_qkv, W_proj, attn_bias,
                                            xb, wqkvb, wprojb, biasB);

    gemm_qkv_fused_kernel<<<dim3(16, 24), 512, 0, stream>>>(
        xb, wqkvb, q_bias, v_bias, scale_mul, Qw, Kw, Vp);

    attn_kernel<<<dim3(32, 16), 512, 0, stream>>>(Qw, Kw, Vp, biasB, Oc);

    gemm_proj_kernel<<<dim3(32, 8), 256, 0, stream>>>(
        Oc, wprojb, out, b_proj, 4096, 1024, 1024);
}

// Round 22
// 162.727 us; speedup vs baseline: 1.0461x; 1.0461x over previous
//
#include <hip/hip_runtime.h>

// Pipeline (4 dispatches): cvt3+bias_prep -> GEMM qkv + fused bias/l2norm/scale/split
//   (V written directly transposed+permuted) -> flash attn (8 waves QBLK=128, no split)
//   -> GEMM proj(f32+bias)
// B=2 L=2048 C=1024 H=16 D=64. All matmuls bf16 MFMA 16x16x32, f32 accumulate.

typedef __bf16 bf16x8 __attribute__((ext_vector_type(8)));
typedef __bf16 bf16x4 __attribute__((ext_vector_type(4)));
typedef float  f32x4  __attribute__((ext_vector_type(4)));

#define BB 2
#define LL 2048
#define CC 1024
#define HH 16
#define DD 64
#define LOG2E 1.44269504088896f

__device__ __forceinline__ f32x4 mfma_16x16x32(bf16x8 a, bf16x8 b, f32x4 c) {
    return __builtin_amdgcn_mfma_f32_16x16x32_bf16(a, b, c, 0, 0, 0);
}

// async global->LDS, 16B per lane; LDS dest = wave-uniform base + lane*16
__device__ __forceinline__ void gload_lds16(const __bf16* g, __bf16* lds) {
    __builtin_amdgcn_global_load_lds(
        (const __attribute__((address_space(1))) unsigned int*)g,
        (__attribute__((address_space(3))) unsigned int*)lds,
        16, 0, 0);
}

__device__ __forceinline__ unsigned pk_bf16(float a, float b) {
    unsigned short ua = __builtin_bit_cast(unsigned short, (__bf16)a);
    unsigned short ub = __builtin_bit_cast(unsigned short, (__bf16)b);
    return (unsigned)ua | ((unsigned)ub << 16);
}

// ---------------- merged: f32->bf16 cvt (blocks 0..8191) + bias_prep (8192..10239) -------
__global__ __launch_bounds__(256) void cvt3b_kernel(
    const float* __restrict__ x, const float* __restrict__ wq, const float* __restrict__ wp,
    const float* __restrict__ bias,
    __bf16* __restrict__ xb, __bf16* __restrict__ wqb, __bf16* __restrict__ wpb,
    __bf16* __restrict__ bias_bf) {
    const int tid = threadIdx.x;
    if (blockIdx.x < 8192) {
        const int i = blockIdx.x * 256 + tid;   // f32x4 index, 2097152 total
        const float* src; __bf16* dst; int off;
        if (i < 1048576)      { src = x;  dst = xb;  off = i; }
        else if (i < 1835008) { src = wq; dst = wqb; off = i - 1048576; }
        else                  { src = wp; dst = wpb; off = i - 1835008; }
        float4 v = reinterpret_cast<const float4*>(src)[off];
        bf16x4 o;
        o[0] = (__bf16)v.x; o[1] = (__bf16)v.y; o[2] = (__bf16)v.z; o[3] = (__bf16)v.w;
        reinterpret_cast<bf16x4*>(dst)[off] = o;
    } else {
        __shared__ float wmax[4];
        const int l = blockIdx.x - 8192;        // bias row 0..2047
        const int w = tid >> 6;
        float4 a = reinterpret_cast<const float4*>(bias + (size_t)l * 2048)[tid];
        float4 b = reinterpret_cast<const float4*>(bias + (size_t)l * 2048 + 1024)[tid];
        float m = fmaxf(fmaxf(fmaxf(a.x, a.y), fmaxf(a.z, a.w)),
                        fmaxf(fmaxf(b.x, b.y), fmaxf(b.z, b.w)));
#pragma unroll
        for (int off = 1; off < 64; off <<= 1) m = fmaxf(m, __shfl_xor(m, off, 64));
        if ((tid & 63) == 0) wmax[w] = m;
        __syncthreads();
        float M = fmaxf(fmaxf(wmax[0], wmax[1]), fmaxf(wmax[2], wmax[3]));
        bf16x4 o0, o1;
        o0[0] = (__bf16)((a.x - M) * LOG2E); o0[1] = (__bf16)((a.y - M) * LOG2E);
        o0[2] = (__bf16)((a.z - M) * LOG2E); o0[3] = (__bf16)((a.w - M) * LOG2E);
        o1[0] = (__bf16)((b.x - M) * LOG2E); o1[1] = (__bf16)((b.y - M) * LOG2E);
        o1[2] = (__bf16)((b.z - M) * LOG2E); o1[3] = (__bf16)((b.w - M) * LOG2E);
        reinterpret_cast<bf16x4*>(bias_bf + (size_t)l * 2048)[tid] = o0;
        reinterpret_cast<bf16x4*>(bias_bf + (size_t)l * 2048 + 1024)[tid] = o1;
    }
}

// ---------------- QKV GEMM + fused bias/l2norm/scale/split; V written directly as
//                  Vp (B,H,D,perm(L)): pos = (k[3:2]<<3)|(k[4]<<2)|k[1:0] per 32-block ----
__global__ __launch_bounds__(256) void gemm_qkv_fused_kernel(
    const __bf16* __restrict__ A, const __bf16* __restrict__ Bm,
    const float* __restrict__ q_bias, const float* __restrict__ v_bias,
    const float* __restrict__ scale_mul,
    __bf16* __restrict__ Qw, __bf16* __restrict__ Kw, __bf16* __restrict__ Vp) {
    __shared__ __bf16 As[128 * 64];   // LDS[row][c] = A[row][c ^ ((row&7)<<4)]  (byte view)
    __shared__ __bf16 Bs[128 * 64];
    const int tid = threadIdx.x;
    const int K = 1024;
    const int nwg = gridDim.x * gridDim.y;
    const int flat = blockIdx.y * gridDim.x + blockIdx.x;
    const int wg = (flat & 7) * (nwg >> 3) + (flat >> 3);
    const int m0 = (wg % gridDim.x) * 128, n0 = (wg / gridDim.x) * 128;
    const int w  = tid >> 6, l = tid & 63;
    const int wr = (w >> 1) * 64, wc = (w & 1) * 64;
    const int lr = l & 15, lg = l >> 4;
    const int rmask = (lr & 7) << 4;
    f32x4 acc[4][4] = {};
    const int lrow = l >> 3;
    const int celem = (((l & 7) ^ lrow) << 3);

    for (int kt = 0; kt < K; kt += 64) {
        __syncthreads();
#pragma unroll
        for (int i = 0; i < 4; ++i) {
            const int row = w * 32 + i * 8;
            gload_lds16(A + (size_t)(m0 + row + lrow) * K + kt + celem, &As[row * 64]);
            gload_lds16(Bm + (size_t)(n0 + row + lrow) * K + kt + celem, &Bs[row * 64]);
        }
        asm volatile("s_waitcnt vmcnt(0)" ::: "memory");
        __syncthreads();
#pragma unroll
        for (int kk = 0; kk < 2; ++kk) {
            bf16x8 af[4], bfr[4];
#pragma unroll
            for (int m = 0; m < 4; ++m)
                af[m] = *reinterpret_cast<const bf16x8*>(
                    (char*)As + (wr + m * 16 + lr) * 128 + ((kk * 64 + lg * 16) ^ rmask));
#pragma unroll
            for (int n = 0; n < 4; ++n)
                bfr[n] = *reinterpret_cast<const bf16x8*>(
                    (char*)Bs + (wc + n * 16 + lr) * 128 + ((kk * 64 + lg * 16) ^ rmask));
#pragma unroll
            for (int m = 0; m < 4; ++m)
#pragma unroll
                for (int n = 0; n < 4; ++n)
                    acc[m][n] = mfma_16x16x32(af[m], bfr[n], acc[m][n]);
        }
    }

    // ---- fused epilogue ----
    const int gcbase = n0 + wc;
    const int type = gcbase >> 10;           // 0=q, 1=k, 2=v
    const int h = (gcbase & 1023) >> 6;
    float qscale = 1.0f;
    if (type == 0) qscale = __expf(fminf(scale_mul[h], 4.60517019f)) * LOG2E;
    __bf16* dst = (type == 0) ? Qw : Kw;

#pragma unroll
    for (int m = 0; m < 4; ++m) {
        if (type != 1) {                     // q/v bias (k has zero bias)
            const float* bptr = (type == 0) ? q_bias : v_bias;
#pragma unroll
            for (int n = 0; n < 4; ++n) {
                float bv = bptr[(gcbase & 1023) + n * 16 + lr];
#pragma unroll
                for (int r = 0; r < 4; ++r) acc[m][n][r] += bv;
            }
        }
        const int rowg = m0 + wr + m * 16 + lg * 4;
        if (type < 2) {
            float rs[4];
#pragma unroll
            for (int r = 0; r < 4; ++r) {
                float ss = 0.f;
#pragma unroll
                for (int n = 0; n < 4; ++n) ss += acc[m][n][r] * acc[m][n][r];
                rs[r] = ss;
            }
#pragma unroll
            for (int off = 1; off < 16; off <<= 1)
#pragma unroll
                for (int r = 0; r < 4; ++r) rs[r] += __shfl_xor(rs[r], off, 64);
#pragma unroll
            for (int r = 0; r < 4; ++r)
                rs[r] = ((type == 0) ? qscale : 1.0f) / fmaxf(sqrtf(rs[r]), 1e-12f);
#pragma unroll
            for (int n = 0; n < 4; ++n) {
                const int d = n * 16 + lr;
#pragma unroll
                for (int r = 0; r < 4; ++r) {
                    const int row = rowg + r;
                    const int bb = row >> 11, ll = row & 2047;
                    dst[((size_t)((bb << 4) + h) * 2048 + ll) * 64 + d] =
                        (__bf16)(acc[m][n][r] * rs[r]);
                }
            }
        } else {
            // V: direct transposed+permuted write. rowg%4==0, so the 4 rows map to
            // 4 consecutive Vp positions: posb = (k3_2<<3)|(k4<<2), +r.
            const int bb = rowg >> 11, ll0 = rowg & 2047;
            const int posb = (ll0 & ~31) | (((ll0 >> 2) & 3) << 3) | (((ll0 >> 4) & 1) << 2);
#pragma unroll
            for (int n = 0; n < 4; ++n) {
                const int d = n * 16 + lr;
                bf16x4 vv;
#pragma unroll
                for (int r = 0; r < 4; ++r) vv[r] = (__bf16)acc[m][n][r];
                *reinterpret_cast<bf16x4*>(
                    Vp + ((size_t)((bb << 4) + h) * 64 + d) * 2048 + posb) = vv;
            }
        }
    }
}

// ---------------- GEMM proj: C = A*B^T + bias (f32 out), m97 + XCD swz ----------
__global__ __launch_bounds__(256) void gemm_proj_kernel(
    const __bf16* __restrict__ A, const __bf16* __restrict__ Bm,
    float* __restrict__ Cf, const float* __restrict__ bias, int M, int N, int K) {
    __shared__ __bf16 As[128 * 64];
    __shared__ __bf16 Bs[128 * 64];
    const int tid = threadIdx.x;
    const int nwg = gridDim.x * gridDim.y;
    const int flat = blockIdx.y * gridDim.x + blockIdx.x;
    const int wg = (flat & 7) * (nwg >> 3) + (flat >> 3);
    const int m0 = (wg % gridDim.x) * 128, n0 = (wg / gridDim.x) * 128;
    const int w  = tid >> 6, l = tid & 63;
    const int wr = (w >> 1) * 64, wc = (w & 1) * 64;
    const int lr = l & 15, lg = l >> 4;
    const int rmask = (lr & 7) << 4;
    f32x4 acc[4][4] = {};
    const int lrow = l >> 3;
    const int celem = (((l & 7) ^ lrow) << 3);

    for (int kt = 0; kt < K; kt += 64) {
        __syncthreads();
#pragma unroll
        for (int i = 0; i < 4; ++i) {
            const int row = w * 32 + i * 8;
            gload_lds16(A + (size_t)(m0 + row + lrow) * K + kt + celem, &As[row * 64]);
            gload_lds16(Bm + (size_t)(n0 + row + lrow) * K + kt + celem, &Bs[row * 64]);
        }
        asm volatile("s_waitcnt vmcnt(0)" ::: "memory");
        __syncthreads();
#pragma unroll
        for (int kk = 0; kk < 2; ++kk) {
            bf16x8 af[4], bfr[4];
#pragma unroll
            for (int m = 0; m < 4; ++m)
                af[m] = *reinterpret_cast<const bf16x8*>(
                    (char*)As + (wr + m * 16 + lr) * 128 + ((kk * 64 + lg * 16) ^ rmask));
#pragma unroll
            for (int n = 0; n < 4; ++n)
                bfr[n] = *reinterpret_cast<const bf16x8*>(
                    (char*)Bs + (wc + n * 16 + lr) * 128 + ((kk * 64 + lg * 16) ^ rmask));
#pragma unroll
            for (int m = 0; m < 4; ++m)
#pragma unroll
                for (int n = 0; n < 4; ++n)
                    acc[m][n] = mfma_16x16x32(af[m], bfr[n], acc[m][n]);
        }
    }
#pragma unroll
    for (int m = 0; m < 4; ++m)
#pragma unroll
        for (int n = 0; n < 4; ++n) {
            const int row = m0 + wr + m * 16 + lg * 4;
            const int col = n0 + wc + n * 16 + lr;
#pragma unroll
            for (int r = 0; r < 4; ++r)
                Cf[(size_t)(row + r) * N + col] = acc[m][n][r] + bias[col];
        }
}

// ---------------- flash attention: 8 waves (512 thr), QBLK=128, NO KV-split ----------
// grid (bh=32, qb=16) = 512 blocks = exact 2/CU at (512,6); each block runs all 32
// kb-tiles and writes normalized bf16 output directly (inv = 1/ls, ls rows = Oa rows).
// NOTE: (512,6) + natural bh-fastest dispatch order is load-bearing (R15 lesson).
__global__ __launch_bounds__(512, 6) void attn_kernel(
    const __bf16* __restrict__ Q, const __bf16* __restrict__ K,
    const __bf16* __restrict__ Vp, const __bf16* __restrict__ biasB,
    __bf16* __restrict__ Octx) {
    __shared__ __bf16 KVs[2][2][64 * 64];   // [buf][K/V]; LDS[row][c]=G[row][c^((row&7)<<4)]
    const int bh = blockIdx.x, qb = blockIdx.y;
    const int tid = threadIdx.x;
    const int w = tid >> 6, l = tid & 63;
    const int lr = l & 15, lg = l >> 4;
    const int rmask = (lr & 7) << 4;
    const int b = bh >> 4, h = bh & 15;
    const size_t base = (size_t)bh * LL * DD;

    const int gq = qb * 128 + w * 16 + lr;
    bf16x8 qf[2];
    qf[0] = *reinterpret_cast<const bf16x8*>(Q + base + (size_t)gq * 64 + lg * 8);
    qf[1] = *reinterpret_cast<const bf16x8*>(Q + base + (size_t)gq * 64 + 32 + lg * 8);
    const __bf16* brow = biasB + (size_t)gq * 2048 + lg * 4;

    bf16x8 ones;
#pragma unroll
    for (int j = 0; j < 8; ++j) ones[j] = (__bf16)1.0f;

    // staging: wave w covers rows [w*8, w*8+8); lane: row w*8+(l>>3), 8 elems at (l&7)*8
    const int srow = w * 8 + (l >> 3);
    const int sce  = (l & 7) * 8;                  // element col
    const int smask = (srow & 7) << 4;             // (l>>3)<<4
    const __bf16* kgbase = K  + base + (size_t)srow * 64   + sce;
    const __bf16* vgbase = Vp + base + (size_t)srow * 2048 + sce;

    bf16x8 k0, v0;
    auto stage_regs = [&](int kb) {
        k0 = *reinterpret_cast<const bf16x8*>(kgbase + (size_t)kb * 64 * 64);
        v0 = *reinterpret_cast<const bf16x8*>(vgbase + kb * 64);
    };
    auto write_lds = [&](int buf) {
        *reinterpret_cast<bf16x8*>((char*)KVs[buf][0] + srow * 128 + ((sce * 2) ^ smask)) = k0;
        *reinterpret_cast<bf16x8*>((char*)KVs[buf][1] + srow * 128 + ((sce * 2) ^ smask)) = v0;
    };

    stage_regs(0);
    write_lds(0);

    f32x4 Oa[4] = {};
    f32x4 ls = {};
    int cur = 0;

    bf16x4 bcur[4];
#pragma unroll
    for (int t = 0; t < 4; ++t)
        bcur[t] = *reinterpret_cast<const bf16x4*>(brow + t * 16);

    for (int kb = 0; kb < 32; ++kb) {
        __syncthreads();                    // buf[cur] published; buf[cur^1] free
        if (kb < 31) stage_regs(kb + 1);

        bf16x4 bnext[4];
        if (kb < 31) {
#pragma unroll
            for (int t = 0; t < 4; ++t)
                bnext[t] = *reinterpret_cast<const bf16x4*>(brow + (kb + 1) * 64 + t * 16);
        }

        const char* Kc = (const char*)KVs[cur][0];
        const char* Vc = (const char*)KVs[cur][1];

        // acc init = bias'(bf16); no cexp (cancels in O = sum(pv)/sum(p))
        f32x4 sa[4];
#pragma unroll
        for (int t = 0; t < 4; ++t)
#pragma unroll
            for (int r = 0; r < 4; ++r)
                sa[t][r] = (float)bcur[t][r];

        // S^T·log2e + bias' : lane q=lr, k = 16t+4lg+r
#pragma unroll
        for (int t = 0; t < 4; ++t) {
            const char* kr = Kc + (t * 16 + lr) * 128;
            bf16x8 kf0 = *reinterpret_cast<const bf16x8*>(kr + ((lg * 16) ^ rmask));
            bf16x8 kf1 = *reinterpret_cast<const bf16x8*>(kr + ((64 + lg * 16) ^ rmask));
            sa[t] = mfma_16x16x32(kf0, qf[0], sa[t]);
            sa[t] = mfma_16x16x32(kf1, qf[1], sa[t]);
        }

        // softmax: p = exp2(sa); pack lane-local values into A-operand slots
        float p[4][4];
#pragma unroll
        for (int t = 0; t < 4; ++t)
#pragma unroll
            for (int r = 0; r < 4; ++r)
                p[t][r] = exp2f(sa[t][r]);
        union Upa { unsigned u[4]; bf16x8 v; } pa0, pa1;
        pa0.u[0] = pk_bf16(p[0][0], p[0][1]); pa0.u[1] = pk_bf16(p[0][2], p[0][3]);
        pa0.u[2] = pk_bf16(p[1][0], p[1][1]); pa0.u[3] = pk_bf16(p[1][2], p[1][3]);
        pa1.u[0] = pk_bf16(p[2][0], p[2][1]); pa1.u[1] = pk_bf16(p[2][2], p[2][3]);
        pa1.u[2] = pk_bf16(p[3][0], p[3][1]); pa1.u[3] = pk_bf16(p[3][2], p[3][3]);

        // row-sum via MFMA (B = ones): ls rows = Oa rows
        ls = mfma_16x16x32(pa0.v, ones, ls);
        ls = mfma_16x16x32(pa1.v, ones, ls);

        // O += P·V : V pre-permuted globally -> contiguous b128 reads (same pattern as K)
#pragma unroll
        for (int t = 0; t < 4; ++t) {
            const char* vr = Vc + (t * 16 + lr) * 128;
            bf16x8 vf0 = *reinterpret_cast<const bf16x8*>(vr + ((lg * 16) ^ rmask));
            bf16x8 vf1 = *reinterpret_cast<const bf16x8*>(vr + ((64 + lg * 16) ^ rmask));
            Oa[t] = mfma_16x16x32(pa0.v, vf0, Oa[t]);
            Oa[t] = mfma_16x16x32(pa1.v, vf1, Oa[t]);
        }

        if (kb < 31) {
            write_lds(cur ^ 1);             // write-late; dep on loads forces vmcnt
#pragma unroll
            for (int t = 0; t < 4; ++t) bcur[t] = bnext[t];
        }
        cur ^= 1;
    }

    // normalized bf16 output direct (inv from MFMA row-sum; ls rows == Oa rows)
    float inv[4];
#pragma unroll
    for (int r = 0; r < 4; ++r) inv[r] = 1.0f / ls[r];
#pragma unroll
    for (int t = 0; t < 4; ++t)
#pragma unroll
        for (int r = 0; r < 4; ++r) {
            const int row = qb * 128 + w * 16 + lg * 4 + r;
            Octx[((size_t)(b * 2048 + row)) * 1024 + h * 64 + t * 16 + lr] =
                (__bf16)(Oa[t][r] * inv[r]);
        }
}

// ---------------- launch ----------------
extern "C" void kernel_launch(void* const* d_in, const int* in_sizes, int n_in,
                              void* d_out, int out_size, void* d_ws, size_t ws_size,
                              hipStream_t stream) {
    const float* x         = (const float*)d_in[0];
    const float* attn_bias = (const float*)d_in[1];
    const float* W_qkv     = (const float*)d_in[2];
    const float* q_bias    = (const float*)d_in[3];
    const float* v_bias    = (const float*)d_in[4];
    const float* scale_mul = (const float*)d_in[5];
    const float* W_proj    = (const float*)d_in[6];
    const float* b_proj    = (const float*)d_in[7];
    float* out = (float*)d_out;

    char* ws = (char*)d_ws;
    size_t off = 0;
    auto alloc = [&](size_t bytes) {
        void* p = ws + off;
        off = (off + bytes + 255) & ~(size_t)255;
        return p;
    };
    __bf16* xb      = (__bf16*)alloc((size_t)4096 * 1024 * 2);         //  8 MB
    __bf16* wqkvb   = (__bf16*)alloc((size_t)3072 * 1024 * 2);         //  6 MB
    __bf16* wprojb  = (__bf16*)alloc((size_t)1024 * 1024 * 2);         //  2 MB
    __bf16* Qw      = (__bf16*)alloc((size_t)BB * HH * LL * DD * 2);   //  8 MB
    __bf16* Kw      = (__bf16*)alloc((size_t)BB * HH * LL * DD * 2);   //  8 MB
    __bf16* Oc      = (__bf16*)alloc((size_t)4096 * 1024 * 2);         //  8 MB
    __bf16* biasB   = (__bf16*)alloc((size_t)2048 * 2048 * 2);         //  8 MB
    __bf16* Vp      = (__bf16*)alloc((size_t)BB * HH * LL * DD * 2);   //  8 MB

    cvt3b_kernel<<<10240, 256, 0, stream>>>(x, W_qkv, W_proj, attn_bias,
                                            xb, wqkvb, wprojb, biasB);

    gemm_qkv_fused_kernel<<<dim3(32, 24), 256, 0, stream>>>(
        xb, wqkvb, q_bias, v_bias, scale_mul, Qw, Kw, Vp);

    attn_kernel<<<dim3(32, 16), 512, 0, stream>>>(Qw, Kw, Vp, biasB, Oc);

    gemm_proj_kernel<<<dim3(32, 8), 256, 0, stream>>>(
        Oc, wprojb, out, b_proj, 4096, 1024, 1024);
}